// Round 6
// baseline (634.585 us; speedup 1.0000x reference)
//
#include <hip/hip_runtime.h>
#include <cstdint>
#include <cstddef>

typedef unsigned short u16;
typedef __bf16 bf16_t;
typedef bf16_t bf16x8 __attribute__((ext_vector_type(8)));
typedef float f32x4 __attribute__((ext_vector_type(4)));

#define DEV __device__ __forceinline__
#define AS1 __attribute__((address_space(1)))
#define AS3 __attribute__((address_space(3)))

DEV u16 f2bf(float f) {
  unsigned u = __float_as_uint(f);
  u += 0x7fffu + ((u >> 16) & 1u);
  return (u16)(u >> 16);
}
DEV float bf2f(u16 h) {
  return __uint_as_float(((unsigned)h) << 16);
}

// ---------------------------------------------------------------- converts
struct Cvt9 {
  const float* s[9];
  u16* d[9];
  long cumv[10];
};

__global__ __launch_bounds__(256)
void convert_batch(Cvt9 jobs) {
  const long total = jobs.cumv[9];
  for (long i = (long)blockIdx.x * 256 + threadIdx.x; i < total;
       i += (long)gridDim.x * 256) {
    int j = 0;
#pragma unroll
    for (int t = 0; t < 8; ++t)
      if (i >= jobs.cumv[t + 1]) j = t + 1;
    const long e = (i - jobs.cumv[j]) * 4;
    float4 v = *(const float4*)(jobs.s[j] + e);
    ushort4 o;
    o.x = f2bf(v.x); o.y = f2bf(v.y); o.z = f2bf(v.z); o.w = f2bf(v.w);
    *(ushort4*)(jobs.d[j] + e) = o;
  }
}

__global__ __launch_bounds__(256)
void build_acat(const float* __restrict__ q, const float* __restrict__ it,
                u16* __restrict__ dst) {
  const long total = 16384l * 2048 / 4;
  for (long i = (long)blockIdx.x * 256 + threadIdx.x; i < total;
       i += (long)gridDim.x * 256) {
    long e = i * 4;
    int m = (int)(e >> 11);
    int k = (int)(e & 2047);
    const float* s = (k < 1024) ? (q + (long)m * 1024 + k)
                                : (it + (long)m * 1024 + (k - 1024));
    float4 v = *(const float4*)s;
    ushort4 o;
    o.x = f2bf(v.x); o.y = f2bf(v.y); o.z = f2bf(v.z); o.w = f2bf(v.w);
    *(ushort4*)(dst + e) = o;
  }
}

// ---------------------------------------------------------------- layernorm
__global__ __launch_bounds__(256)
void ln_rows(const float* __restrict__ x, const float* __restrict__ g,
             const float* __restrict__ b, u16* __restrict__ out) {
  __shared__ float red[8];
  const int row = blockIdx.x, tid = threadIdx.x;
  const float* xr = x + (size_t)row * 1024;
  float4 v = *(const float4*)(xr + tid * 4);
  float s = v.x + v.y + v.z + v.w;
  float ss = v.x * v.x + v.y * v.y + v.z * v.z + v.w * v.w;
#pragma unroll
  for (int o = 32; o > 0; o >>= 1) { s += __shfl_xor(s, o); ss += __shfl_xor(ss, o); }
  if ((tid & 63) == 0) { red[tid >> 6] = s; red[4 + (tid >> 6)] = ss; }
  __syncthreads();
  s = red[0] + red[1] + red[2] + red[3];
  ss = red[4] + red[5] + red[6] + red[7];
  const float mean = s * 0.0009765625f;
  const float var = ss * 0.0009765625f - mean * mean;
  const float rinv = rsqrtf(var + 1e-5f);
  const int c = tid * 4;
  float4 gg = *(const float4*)(g + c);
  float4 bb = *(const float4*)(b + c);
  ushort4 o4;
  o4.x = f2bf((v.x - mean) * rinv * gg.x + bb.x);
  o4.y = f2bf((v.y - mean) * rinv * gg.y + bb.y);
  o4.z = f2bf((v.z - mean) * rinv * gg.z + bb.z);
  o4.w = f2bf((v.w - mean) * rinv * gg.w + bb.w);
  *(ushort4*)(out + (size_t)row * 1024 + c) = o4;
}

__global__ __launch_bounds__(256)
void ln_kv(const float* __restrict__ winp,
           const float* __restrict__ gk, const float* __restrict__ bk,
           const float* __restrict__ gv, const float* __restrict__ bv,
           u16* __restrict__ kout, u16* __restrict__ vout) {
  __shared__ float red[8];
  const int m = blockIdx.x, tid = threadIdx.x;
  const int b = m / 576, rem = m % 576;
  const int qw = rem / 36, w = rem % 36;
  const int gidx = (qw >> 2) * 144 + (w / 6) * 24 + (qw & 3) * 6 + (w % 6);
  const float* xr = winp + ((size_t)b * 576 + gidx) * 1024;
  float4 v = *(const float4*)(xr + tid * 4);
  float s = v.x + v.y + v.z + v.w;
  float ss = v.x * v.x + v.y * v.y + v.z * v.z + v.w * v.w;
#pragma unroll
  for (int o = 32; o > 0; o >>= 1) { s += __shfl_xor(s, o); ss += __shfl_xor(ss, o); }
  if ((tid & 63) == 0) { red[tid >> 6] = s; red[4 + (tid >> 6)] = ss; }
  __syncthreads();
  s = red[0] + red[1] + red[2] + red[3];
  ss = red[4] + red[5] + red[6] + red[7];
  const float mean = s * 0.0009765625f;
  const float var = ss * 0.0009765625f - mean * mean;
  const float rinv = rsqrtf(var + 1e-5f);
  const int c = tid * 4;
  float4 gg = *(const float4*)(gk + c);
  float4 bb = *(const float4*)(bk + c);
  float4 g2 = *(const float4*)(gv + c);
  float4 b2 = *(const float4*)(bv + c);
  float nx = (v.x - mean) * rinv, ny = (v.y - mean) * rinv;
  float nz = (v.z - mean) * rinv, nw = (v.w - mean) * rinv;
  ushort4 ok, ov;
  ok.x = f2bf(nx * gg.x + bb.x); ok.y = f2bf(ny * gg.y + bb.y);
  ok.z = f2bf(nz * gg.z + bb.z); ok.w = f2bf(nw * gg.w + bb.w);
  ov.x = f2bf(nx * g2.x + b2.x); ov.y = f2bf(ny * g2.y + b2.y);
  ov.z = f2bf(nz * g2.z + b2.z); ov.w = f2bf(nw * g2.w + b2.w);
  *(ushort4*)(kout + (size_t)m * 1024 + c) = ok;
  *(ushort4*)(vout + (size_t)m * 1024 + c) = ov;
}

// ---------------------------------------------------------------- GEMM 256x256
// C[M,N] = A[M,K] * B[N,K]^T  (bf16 in, fp32 acc).  N == 1024.
// 512 thr / 8 waves (2M x 4N), per-wave 128x64 C.  BK=32, 4-slot circular
// LDS (128 KiB), depth-3 prefetch with counted vmcnt(8), ONE s_barrier per
// K-step (T3+T4), setprio around MFMA cluster (T5), XCD-chunked grid (T1).
//
// Bank swizzle: LDS row stride 32 elems (64 B); slot chunk p at row r holds
// global k-chunk p ^ ((r>>1)&3).  Write side: global source column carries
// the inverse permutation (LDS dest stays linear for global_load_lds);
// read side XORs the same key ((R>>1)&3 == (fr>>1)&3 since R-fr = 16m).
//
// Pipeline safety: stage at step t targets slot (t+3)&3 == (t-1)&3 whose
// reads completed before step t-1's barrier (MFMA reg-deps force lgkmcnt);
// vmcnt(8) at step t leaves only stages t+2,t+3 in flight => tile t+1 is
// resident before the barrier that precedes its reads.  Tail: vmcnt(4), (0).
// EPI: 0 = bf16 store, 1 = f32 store, 2 = f32 acc+addF, 3 = gelu->bf16
template <int EPI>
__global__ __launch_bounds__(512, 2)
void gemm256(const u16* __restrict__ A, const u16* __restrict__ Bw,
             u16* __restrict__ outB, float* __restrict__ outF,
             const float* __restrict__ addF, int M, int N, int K) {
  __shared__ __align__(16) u16 As[4][8192];
  __shared__ __align__(16) u16 Bs[4][8192];
  const int tid = threadIdx.x;
  const int wave = tid >> 6, lane = tid & 63;
  const int fr = lane & 15, fq = lane >> 4;
  // XCD-chunked swizzle: nwg % 8 == 0 (grids 256 / 144)
  const int swz = (blockIdx.x & 7) * ((int)gridDim.x >> 3) + (blockIdx.x >> 3);
  const int brow = (swz >> 2) << 8;   // N=1024 -> 4 col tiles
  const int bcol = (swz & 3) << 8;

  // staging: thread t covers (row = q*128 + t/4, chunk = t&3), 2 issues per mat
  const int srow = tid >> 2;
  const int cgo = ((tid & 3) ^ ((srow >> 1) & 3)) << 3;  // inverse-swizzled col
  const u16* pa0 = A + (size_t)(brow + srow) * K + cgo;
  const u16* pa1 = pa0 + (size_t)128 * K;
  const u16* pb0 = Bw + (size_t)(bcol + srow) * K + cgo;
  const u16* pb1 = pb0 + (size_t)128 * K;

  f32x4 acc[8][4];
#pragma unroll
  for (int mf = 0; mf < 8; ++mf)
#pragma unroll
    for (int nf = 0; nf < 4; ++nf) acc[mf][nf] = (f32x4){0.f, 0.f, 0.f, 0.f};

  const int cs = (fq ^ ((fr >> 1) & 3)) << 3;            // read-side chunk slot
  const int aoffb = ((wave >> 2) * 128 + fr) * 32 + cs;
  const int boffb = ((wave & 3) * 64 + fr) * 32 + cs;

  auto STAGE = [&](int t) {
    const int slot = t & 3, k0 = t << 5;
    __builtin_amdgcn_global_load_lds((const AS1 void*)(pa0 + k0),
                                     (AS3 void*)&As[slot][wave * 512], 16, 0, 0);
    __builtin_amdgcn_global_load_lds((const AS1 void*)(pa1 + k0),
                                     (AS3 void*)&As[slot][4096 + wave * 512], 16, 0, 0);
    __builtin_amdgcn_global_load_lds((const AS1 void*)(pb0 + k0),
                                     (AS3 void*)&Bs[slot][wave * 512], 16, 0, 0);
    __builtin_amdgcn_global_load_lds((const AS1 void*)(pb1 + k0),
                                     (AS3 void*)&Bs[slot][4096 + wave * 512], 16, 0, 0);
  };

  auto COMPUTE = [&](int t) {
    const u16* la = &As[t & 3][0];
    const u16* lb = &Bs[t & 3][0];
    bf16x8 a[8], b[4];
#pragma unroll
    for (int mf = 0; mf < 8; ++mf) a[mf] = *(const bf16x8*)&la[aoffb + mf * 512];
#pragma unroll
    for (int nf = 0; nf < 4; ++nf) b[nf] = *(const bf16x8*)&lb[boffb + nf * 512];
    __builtin_amdgcn_s_setprio(1);
#pragma unroll
    for (int mf = 0; mf < 8; ++mf)
#pragma unroll
      for (int nf = 0; nf < 4; ++nf)
        acc[mf][nf] = __builtin_amdgcn_mfma_f32_16x16x32_bf16(a[mf], b[nf],
                                                              acc[mf][nf], 0, 0, 0);
    __builtin_amdgcn_s_setprio(0);
  };

  const int nt = K >> 5;  // 32 or 64
  STAGE(0); STAGE(1); STAGE(2);
  asm volatile("s_waitcnt vmcnt(8)" ::: "memory");  // tile 0 resident
  __builtin_amdgcn_s_barrier();
  __builtin_amdgcn_sched_barrier(0);
  for (int t = 0; t < nt - 3; ++t) {
    STAGE(t + 3);
    COMPUTE(t);
    asm volatile("s_waitcnt vmcnt(8)" ::: "memory");  // tile t+1 resident
    __builtin_amdgcn_s_barrier();
    __builtin_amdgcn_sched_barrier(0);
  }
  COMPUTE(nt - 3);
  asm volatile("s_waitcnt vmcnt(4)" ::: "memory");    // tile nt-2 resident
  __builtin_amdgcn_s_barrier();
  __builtin_amdgcn_sched_barrier(0);
  COMPUTE(nt - 2);
  asm volatile("s_waitcnt vmcnt(0)" ::: "memory");    // tile nt-1 resident
  __builtin_amdgcn_s_barrier();
  __builtin_amdgcn_sched_barrier(0);
  COMPUTE(nt - 1);

#pragma unroll
  for (int mf = 0; mf < 8; ++mf) {
    const int row0 = brow + (wave >> 2) * 128 + mf * 16 + fq * 4;
#pragma unroll
    for (int nf = 0; nf < 4; ++nf) {
      const int col = bcol + (wave & 3) * 64 + nf * 16 + fr;
#pragma unroll
      for (int j = 0; j < 4; ++j) {
        const size_t o = (size_t)(row0 + j) * N + col;
        const float vv = acc[mf][nf][j];
        if constexpr (EPI == 0) {
          outB[o] = f2bf(vv);
        } else if constexpr (EPI == 1) {
          outF[o] = vv;
        } else if constexpr (EPI == 2) {
          outF[o] = vv + addF[o];
        } else {
          outB[o] = f2bf(0.5f * vv * (1.0f + erff(vv * 0.70710678118654752f)));
        }
      }
    }
  }
}

// ---------------------------------------------------------------- attention
__global__ __launch_bounds__(256)
void attn_kernel(const u16* __restrict__ q, const u16* __restrict__ k,
                 const u16* __restrict__ v, u16* __restrict__ ao) {
  __shared__ __align__(16) u16 Qs[64 * 64];
  __shared__ __align__(16) u16 Ks[36 * 64];
  __shared__ __align__(16) u16 Vs[36 * 64];
  __shared__ float Ps[64 * 36];
  const int bid = blockIdx.x;
  const int h = bid & 15, qw = (bid >> 4) & 15, b = bid >> 8;
  const int tid = threadIdx.x;
  const size_t qbase = ((size_t)b * 1024) * 1024 + (size_t)h * 64;
  for (int i = tid; i < 64 * 16; i += 256) {
    int l = i >> 4, d4 = (i & 15) * 4;
    *(ushort4*)&Qs[l * 64 + d4] =
        *(const ushort4*)&q[qbase + (size_t)(l * 16 + qw) * 1024 + d4];
  }
  const size_t kvbase = ((size_t)(b * 16 + qw)) * 36 * 1024 + (size_t)h * 64;
  for (int i = tid; i < 36 * 16; i += 256) {
    int w = i >> 4, d4 = (i & 15) * 4;
    *(ushort4*)&Ks[w * 64 + d4] = *(const ushort4*)&k[kvbase + (size_t)w * 1024 + d4];
    *(ushort4*)&Vs[w * 64 + d4] = *(const ushort4*)&v[kvbase + (size_t)w * 1024 + d4];
  }
  __syncthreads();
  const int l = tid >> 2, quad = tid & 3;
  float sc[9];
#pragma unroll
  for (int wi = 0; wi < 9; ++wi) {
    int w = quad * 9 + wi;
    float acc = 0.f;
#pragma unroll
    for (int dd = 0; dd < 64; dd += 4) {
      ushort4 qv = *(const ushort4*)&Qs[l * 64 + dd];
      ushort4 kv = *(const ushort4*)&Ks[w * 64 + dd];
      acc += bf2f(qv.x) * bf2f(kv.x) + bf2f(qv.y) * bf2f(kv.y) +
             bf2f(qv.z) * bf2f(kv.z) + bf2f(qv.w) * bf2f(kv.w);
    }
    sc[wi] = acc * 0.125f;
  }
  float mx = sc[0];
#pragma unroll
  for (int wi = 1; wi < 9; ++wi) mx = fmaxf(mx, sc[wi]);
  mx = fmaxf(mx, __shfl_xor(mx, 1));
  mx = fmaxf(mx, __shfl_xor(mx, 2));
  float sum = 0.f;
#pragma unroll
  for (int wi = 0; wi < 9; ++wi) { sc[wi] = __expf(sc[wi] - mx); sum += sc[wi]; }
  sum += __shfl_xor(sum, 1);
  sum += __shfl_xor(sum, 2);
  const float inv = 1.0f / sum;
#pragma unroll
  for (int wi = 0; wi < 9; ++wi) Ps[l * 36 + quad * 9 + wi] = sc[wi] * inv;
  __syncthreads();
  float o[16];
#pragma unroll
  for (int dd = 0; dd < 16; ++dd) o[dd] = 0.f;
  for (int w = 0; w < 36; ++w) {
    float p = Ps[l * 36 + w];
#pragma unroll
    for (int dd = 0; dd < 16; dd += 4) {
      ushort4 vv = *(const ushort4*)&Vs[w * 64 + quad * 16 + dd];
      o[dd] += p * bf2f(vv.x); o[dd + 1] += p * bf2f(vv.y);
      o[dd + 2] += p * bf2f(vv.z); o[dd + 3] += p * bf2f(vv.w);
    }
  }
  const size_t obase = qbase + (size_t)(l * 16 + qw) * 1024 + quad * 16;
#pragma unroll
  for (int dd = 0; dd < 16; dd += 4) {
    ushort4 ov;
    ov.x = f2bf(o[dd]); ov.y = f2bf(o[dd + 1]);
    ov.z = f2bf(o[dd + 2]); ov.w = f2bf(o[dd + 3]);
    *(ushort4*)&ao[obase + dd] = ov;
  }
}

// ---------------------------------------------------------------- launch
extern "C" void kernel_launch(void* const* d_in, const int* in_sizes, int n_in,
                              void* d_out, int out_size, void* d_ws, size_t ws_size,
                              hipStream_t stream) {
  const float* gctx = (const float*)d_in[1];
  const float* queries = (const float*)d_in[4];
  const float* image_tokens = (const float*)d_in[5];
  const float* W_in = (const float*)d_in[7];
  const float* W_ctx = (const float*)d_in[8];
  const float* ln_q_g = (const float*)d_in[9];
  const float* ln_q_b = (const float*)d_in[10];
  const float* Wq = (const float*)d_in[11];
  const float* ln_k_g = (const float*)d_in[12];
  const float* ln_k_b = (const float*)d_in[13];
  const float* Wk = (const float*)d_in[14];
  const float* ln_v_g = (const float*)d_in[15];
  const float* ln_v_b = (const float*)d_in[16];
  const float* Wv = (const float*)d_in[17];
  const float* Wo = (const float*)d_in[18];
  const float* norm_g = (const float*)d_in[19];
  const float* norm_b = (const float*)d_in[20];
  const float* W1 = (const float*)d_in[21];
  const float* W2 = (const float*)d_in[22];
  float* out = (float*)d_out;

  // ---- workspace arena (136 MiB) ----
  char* ws = (char*)d_ws;
  const size_t MB = 1024 * 1024;
  u16* w_in_b  = (u16*)(ws + 0 * MB);
  u16* w_ctx_b = (u16*)(ws + 4 * MB);
  u16* wq_b    = (u16*)(ws + 6 * MB);
  u16* wk_b    = (u16*)(ws + 8 * MB);
  u16* wv_b    = (u16*)(ws + 10 * MB);
  u16* wo_b    = (u16*)(ws + 12 * MB);
  u16* w1_b    = (u16*)(ws + 14 * MB);
  u16* w2_b    = (u16*)(ws + 16 * MB);
  char* regA = ws + 18 * MB;   // 64 MiB
  char* regB = regA + 64 * MB; // 36 MiB
  char* regC = regB + 36 * MB; // 18 MiB

  u16* acat = (u16*)regA;
  u16* pqln = (u16*)regA;
  u16* qmat = (u16*)(regA + 32 * MB);
  u16* vln  = (u16*)regA;
  u16* aoh  = (u16*)regA;
  u16* xmat = (u16*)(regA + 32 * MB);

  float* winp = (float*)regB;
  u16* kmat = (u16*)regB;
  u16* vmat = (u16*)(regB + 18 * MB);
  u16* gout = (u16*)regB;

  u16* gcb = (u16*)regC;
  u16* kln = (u16*)regC;

  float* pq = out;   // f32 16384x1024, lives in d_out

  Cvt9 jobs;
  const float* srcs[9] = {W_in, W_ctx, Wq, Wk, Wv, Wo, W1, W2, gctx};
  u16* dsts[9] = {w_in_b, w_ctx_b, wq_b, wk_b, wv_b, wo_b, w1_b, w2_b, gcb};
  long sizes[9] = {2048l * 1024, 1048576, 1048576, 1048576, 1048576,
                   1048576, 1048576, 1048576, 9216l * 1024};
  long cum = 0;
  for (int j = 0; j < 9; ++j) {
    jobs.s[j] = srcs[j];
    jobs.d[j] = dsts[j];
    jobs.cumv[j] = cum;
    cum += sizes[j] / 4;
  }
  jobs.cumv[9] = cum;
  convert_batch<<<dim3(2048), dim3(256), 0, stream>>>(jobs);
  build_acat<<<dim3(8192), dim3(256), 0, stream>>>(queries, image_tokens, acat);

  // grids: M=16384 -> 64x4 = 256 blocks; M=9216 -> 36x4 = 144 blocks
  gemm256<1><<<dim3(256), dim3(512), 0, stream>>>(acat, w_in_b, nullptr, pq,
                                                  nullptr, 16384, 1024, 2048);
  ln_rows<<<dim3(16384), dim3(256), 0, stream>>>(pq, ln_q_g, ln_q_b, pqln);
  gemm256<0><<<dim3(256), dim3(512), 0, stream>>>(pqln, wq_b, qmat, nullptr,
                                                  nullptr, 16384, 1024, 1024);
  gemm256<1><<<dim3(144), dim3(512), 0, stream>>>(gcb, w_ctx_b, nullptr, winp,
                                                  nullptr, 9216, 1024, 1024);
  ln_kv<<<dim3(9216), dim3(256), 0, stream>>>(winp, ln_k_g, ln_k_b, ln_v_g,
                                              ln_v_b, kln, vln);
  gemm256<0><<<dim3(144), dim3(512), 0, stream>>>(kln, wk_b, kmat, nullptr,
                                                  nullptr, 9216, 1024, 1024);
  gemm256<0><<<dim3(144), dim3(512), 0, stream>>>(vln, wv_b, vmat, nullptr,
                                                  nullptr, 9216, 1024, 1024);
  attn_kernel<<<dim3(4096), dim3(256), 0, stream>>>(qmat, kmat, vmat, aoh);
  gemm256<2><<<dim3(256), dim3(512), 0, stream>>>(aoh, wo_b, nullptr, pq, pq,
                                                  16384, 1024, 1024);
  ln_rows<<<dim3(16384), dim3(256), 0, stream>>>(pq, norm_g, norm_b, xmat);
  gemm256<3><<<dim3(256), dim3(512), 0, stream>>>(xmat, w1_b, gout, nullptr,
                                                  nullptr, 16384, 1024, 1024);
  gemm256<2><<<dim3(256), dim3(512), 0, stream>>>(gout, w2_b, nullptr, out,
                                                  image_tokens, 16384, 1024, 1024);
}

// Round 7
// 531.828 us; speedup vs baseline: 1.1932x; 1.1932x over previous
//
#include <hip/hip_runtime.h>
#include <cstdint>
#include <cstddef>

typedef unsigned short u16;
typedef __bf16 bf16_t;
typedef bf16_t bf16x8 __attribute__((ext_vector_type(8)));
typedef float f32x4 __attribute__((ext_vector_type(4)));

#define DEV __device__ __forceinline__
#define AS1 __attribute__((address_space(1)))
#define AS3 __attribute__((address_space(3)))

DEV u16 f2bf(float f) {
  unsigned u = __float_as_uint(f);
  u += 0x7fffu + ((u >> 16) & 1u);
  return (u16)(u >> 16);
}
DEV float bf2f(u16 h) {
  return __uint_as_float(((unsigned)h) << 16);
}

// ---------------------------------------------------------------- converts
struct Cvt9 {
  const float* s[9];
  u16* d[9];
  long cumv[10];
};

__global__ __launch_bounds__(256)
void convert_batch(Cvt9 jobs) {
  const long total = jobs.cumv[9];
  for (long i = (long)blockIdx.x * 256 + threadIdx.x; i < total;
       i += (long)gridDim.x * 256) {
    int j = 0;
#pragma unroll
    for (int t = 0; t < 8; ++t)
      if (i >= jobs.cumv[t + 1]) j = t + 1;
    const long e = (i - jobs.cumv[j]) * 4;
    float4 v = *(const float4*)(jobs.s[j] + e);
    ushort4 o;
    o.x = f2bf(v.x); o.y = f2bf(v.y); o.z = f2bf(v.z); o.w = f2bf(v.w);
    *(ushort4*)(jobs.d[j] + e) = o;
  }
}

__global__ __launch_bounds__(256)
void build_acat(const float* __restrict__ q, const float* __restrict__ it,
                u16* __restrict__ dst) {
  const long total = 16384l * 2048 / 4;
  for (long i = (long)blockIdx.x * 256 + threadIdx.x; i < total;
       i += (long)gridDim.x * 256) {
    long e = i * 4;
    int m = (int)(e >> 11);
    int k = (int)(e & 2047);
    const float* s = (k < 1024) ? (q + (long)m * 1024 + k)
                                : (it + (long)m * 1024 + (k - 1024));
    float4 v = *(const float4*)s;
    ushort4 o;
    o.x = f2bf(v.x); o.y = f2bf(v.y); o.z = f2bf(v.z); o.w = f2bf(v.w);
    *(ushort4*)(dst + e) = o;
  }
}

// ---------------------------------------------------------------- layernorm
__global__ __launch_bounds__(256)
void ln_rows(const float* __restrict__ x, const float* __restrict__ g,
             const float* __restrict__ b, u16* __restrict__ out) {
  __shared__ float red[8];
  const int row = blockIdx.x, tid = threadIdx.x;
  const float* xr = x + (size_t)row * 1024;
  float4 v = *(const float4*)(xr + tid * 4);
  float s = v.x + v.y + v.z + v.w;
  float ss = v.x * v.x + v.y * v.y + v.z * v.z + v.w * v.w;
#pragma unroll
  for (int o = 32; o > 0; o >>= 1) { s += __shfl_xor(s, o); ss += __shfl_xor(ss, o); }
  if ((tid & 63) == 0) { red[tid >> 6] = s; red[4 + (tid >> 6)] = ss; }
  __syncthreads();
  s = red[0] + red[1] + red[2] + red[3];
  ss = red[4] + red[5] + red[6] + red[7];
  const float mean = s * 0.0009765625f;
  const float var = ss * 0.0009765625f - mean * mean;
  const float rinv = rsqrtf(var + 1e-5f);
  const int c = tid * 4;
  float4 gg = *(const float4*)(g + c);
  float4 bb = *(const float4*)(b + c);
  ushort4 o4;
  o4.x = f2bf((v.x - mean) * rinv * gg.x + bb.x);
  o4.y = f2bf((v.y - mean) * rinv * gg.y + bb.y);
  o4.z = f2bf((v.z - mean) * rinv * gg.z + bb.z);
  o4.w = f2bf((v.w - mean) * rinv * gg.w + bb.w);
  *(ushort4*)(out + (size_t)row * 1024 + c) = o4;
}

__global__ __launch_bounds__(256)
void ln_kv(const float* __restrict__ winp,
           const float* __restrict__ gk, const float* __restrict__ bk,
           const float* __restrict__ gv, const float* __restrict__ bv,
           u16* __restrict__ kout, u16* __restrict__ vout) {
  __shared__ float red[8];
  const int m = blockIdx.x, tid = threadIdx.x;
  const int b = m / 576, rem = m % 576;
  const int qw = rem / 36, w = rem % 36;
  const int gidx = (qw >> 2) * 144 + (w / 6) * 24 + (qw & 3) * 6 + (w % 6);
  const float* xr = winp + ((size_t)b * 576 + gidx) * 1024;
  float4 v = *(const float4*)(xr + tid * 4);
  float s = v.x + v.y + v.z + v.w;
  float ss = v.x * v.x + v.y * v.y + v.z * v.z + v.w * v.w;
#pragma unroll
  for (int o = 32; o > 0; o >>= 1) { s += __shfl_xor(s, o); ss += __shfl_xor(ss, o); }
  if ((tid & 63) == 0) { red[tid >> 6] = s; red[4 + (tid >> 6)] = ss; }
  __syncthreads();
  s = red[0] + red[1] + red[2] + red[3];
  ss = red[4] + red[5] + red[6] + red[7];
  const float mean = s * 0.0009765625f;
  const float var = ss * 0.0009765625f - mean * mean;
  const float rinv = rsqrtf(var + 1e-5f);
  const int c = tid * 4;
  float4 gg = *(const float4*)(gk + c);
  float4 bb = *(const float4*)(bk + c);
  float4 g2 = *(const float4*)(gv + c);
  float4 b2 = *(const float4*)(bv + c);
  float nx = (v.x - mean) * rinv, ny = (v.y - mean) * rinv;
  float nz = (v.z - mean) * rinv, nw = (v.w - mean) * rinv;
  ushort4 ok, ov;
  ok.x = f2bf(nx * gg.x + bb.x); ok.y = f2bf(ny * gg.y + bb.y);
  ok.z = f2bf(nz * gg.z + bb.z); ok.w = f2bf(nw * gg.w + bb.w);
  ov.x = f2bf(nx * g2.x + b2.x); ov.y = f2bf(ny * g2.y + b2.y);
  ov.z = f2bf(nz * g2.z + b2.z); ov.w = f2bf(nw * g2.w + b2.w);
  *(ushort4*)(kout + (size_t)m * 1024 + c) = ok;
  *(ushort4*)(vout + (size_t)m * 1024 + c) = ov;
}

// ---------------------------------------------------------------- GEMM 256x256
// C[M,N] = A[M,K] * B[N,K]^T  (bf16 in, fp32 acc).  N == 1024, K % 64 == 0.
// 512 thr / 8 waves (2M x 4N), per-wave 128x64.  BK=64, 2 K-tile LDS buffers
// (128 KiB).  m201-style 4-phase K-tile: per phase {ds_read subtile; stage
// issue} | bar | lgkm(0)+schedbar | setprio 16xMFMA | bar.  Stage t+1's
// A-halves at phase 0, B at phase 1 (buffer dead since t-1); single vmcnt(0)
// folded before phase 3's closing barrier (issued >=2 phases earlier -> free).
// Bank swizzle (round-4-verified): LDS slot(row, s) holds global chunk
// s ^ (row&7); stage side inverse-permutes the GLOBAL column, read side XORs.
// EPI: 0 = bf16 store, 1 = f32 store, 2 = f32 acc+addF, 3 = gelu->bf16
template <int EPI>
__global__ __launch_bounds__(512, 2)
void gemm256(const u16* __restrict__ A, const u16* __restrict__ Bw,
             u16* __restrict__ outB, float* __restrict__ outF,
             const float* __restrict__ addF, int M, int N, int K) {
  __shared__ __align__(16) u16 lds[2][2][16384];  // [buf][A/B][256 rows x 64 k]
  const int tid = threadIdx.x;
  const int wave = tid >> 6, lane = tid & 63;
  const int fr = lane & 15, fq = lane >> 4;
  // XCD-chunked swizzle (grids 256 / 144, both % 8 == 0)
  const int swz = (blockIdx.x & 7) * ((int)gridDim.x >> 3) + (blockIdx.x >> 3);
  const int brow = (swz >> 2) << 8;   // N=1024 -> 4 col tiles
  const int bcol = (swz & 3) << 8;

  // staging: thread -> (row = tid>>3 (+64i), chunk = tid&7), LDS dest linear
  const int srow = tid >> 3;
  const int cgo = ((tid & 7) ^ (srow & 7)) << 3;   // inverse-swizzled global col
  const u16* pa0 = A + (size_t)(brow + srow) * K + cgo;
  const u16* pb0 = Bw + (size_t)(bcol + srow) * K + cgo;
  const size_t rstep = (size_t)64 * K;

  f32x4 acc[8][4];
#pragma unroll
  for (int mf = 0; mf < 8; ++mf)
#pragma unroll
    for (int nf = 0; nf < 4; ++nf) acc[mf][nf] = (f32x4){0.f, 0.f, 0.f, 0.f};

  const int fx = fr & 7;
  const int arow = (wave >> 2) * 128 + fr;   // + mh*64 + mf*16
  const int brl = (wave & 3) * 64 + fr;      // + nf*16

  auto STAGE_A = [&](int buf, int kt) {
    const int k0 = kt << 6;
#pragma unroll
    for (int i = 0; i < 4; ++i)
      __builtin_amdgcn_global_load_lds((const AS1 void*)(pa0 + i * rstep + k0),
                                       (AS3 void*)&lds[buf][0][i * 4096 + tid * 8],
                                       16, 0, 0);
  };
  auto STAGE_B = [&](int buf, int kt) {
    const int k0 = kt << 6;
#pragma unroll
    for (int i = 0; i < 4; ++i)
      __builtin_amdgcn_global_load_lds((const AS1 void*)(pb0 + i * rstep + k0),
                                       (AS3 void*)&lds[buf][1][i * 4096 + tid * 8],
                                       16, 0, 0);
  };

  const int NT = K >> 6;
  STAGE_A(0, 0);
  STAGE_B(0, 0);
  asm volatile("s_waitcnt vmcnt(0)" ::: "memory");
  __builtin_amdgcn_s_barrier();

  bf16x8 a[4], b[4];
  for (int t = 0; t < NT; ++t) {
    const u16* la = &lds[t & 1][0][0];
    const u16* lb = &lds[t & 1][1][0];
    const int nxt = (t + 1) & 1;

    // ---- phase 0: ks=0, mh=0 (8 reads) + stage A(t+1)
#pragma unroll
    for (int nf = 0; nf < 4; ++nf)
      b[nf] = *(const bf16x8*)&lb[(brl + nf * 16) * 64 + ((fq ^ fx) << 3)];
#pragma unroll
    for (int mf = 0; mf < 4; ++mf)
      a[mf] = *(const bf16x8*)&la[(arow + mf * 16) * 64 + ((fq ^ fx) << 3)];
    if (t + 1 < NT) STAGE_A(nxt, t + 1);
    __builtin_amdgcn_s_barrier();
    asm volatile("s_waitcnt lgkmcnt(0)" ::: "memory");
    __builtin_amdgcn_sched_barrier(0);
    __builtin_amdgcn_s_setprio(1);
#pragma unroll
    for (int mf = 0; mf < 4; ++mf)
#pragma unroll
      for (int nf = 0; nf < 4; ++nf)
        acc[mf][nf] = __builtin_amdgcn_mfma_f32_16x16x32_bf16(a[mf], b[nf],
                                                              acc[mf][nf], 0, 0, 0);
    __builtin_amdgcn_s_setprio(0);
    __builtin_amdgcn_s_barrier();

    // ---- phase 1: ks=0, mh=1 (4 reads) + stage B(t+1)
#pragma unroll
    for (int mf = 0; mf < 4; ++mf)
      a[mf] = *(const bf16x8*)&la[(arow + 64 + mf * 16) * 64 + ((fq ^ fx) << 3)];
    if (t + 1 < NT) STAGE_B(nxt, t + 1);
    __builtin_amdgcn_s_barrier();
    asm volatile("s_waitcnt lgkmcnt(0)" ::: "memory");
    __builtin_amdgcn_sched_barrier(0);
    __builtin_amdgcn_s_setprio(1);
#pragma unroll
    for (int mf = 0; mf < 4; ++mf)
#pragma unroll
      for (int nf = 0; nf < 4; ++nf)
        acc[4 + mf][nf] = __builtin_amdgcn_mfma_f32_16x16x32_bf16(a[mf], b[nf],
                                                                  acc[4 + mf][nf], 0, 0, 0);
    __builtin_amdgcn_s_setprio(0);
    __builtin_amdgcn_s_barrier();

    // ---- phase 2: ks=1, mh=0 (8 reads)
#pragma unroll
    for (int nf = 0; nf < 4; ++nf)
      b[nf] = *(const bf16x8*)&lb[(brl + nf * 16) * 64 + (((4 + fq) ^ fx) << 3)];
#pragma unroll
    for (int mf = 0; mf < 4; ++mf)
      a[mf] = *(const bf16x8*)&la[(arow + mf * 16) * 64 + (((4 + fq) ^ fx) << 3)];
    __builtin_amdgcn_s_barrier();
    asm volatile("s_waitcnt lgkmcnt(0)" ::: "memory");
    __builtin_amdgcn_sched_barrier(0);
    __builtin_amdgcn_s_setprio(1);
#pragma unroll
    for (int mf = 0; mf < 4; ++mf)
#pragma unroll
      for (int nf = 0; nf < 4; ++nf)
        acc[mf][nf] = __builtin_amdgcn_mfma_f32_16x16x32_bf16(a[mf], b[nf],
                                                              acc[mf][nf], 0, 0, 0);
    __builtin_amdgcn_s_setprio(0);
    __builtin_amdgcn_s_barrier();

    // ---- phase 3: ks=1, mh=1 (4 reads); vmcnt(0) before closing barrier
#pragma unroll
    for (int mf = 0; mf < 4; ++mf)
      a[mf] = *(const bf16x8*)&la[(arow + 64 + mf * 16) * 64 + (((4 + fq) ^ fx) << 3)];
    __builtin_amdgcn_s_barrier();
    asm volatile("s_waitcnt lgkmcnt(0)" ::: "memory");
    __builtin_amdgcn_sched_barrier(0);
    __builtin_amdgcn_s_setprio(1);
#pragma unroll
    for (int mf = 0; mf < 4; ++mf)
#pragma unroll
      for (int nf = 0; nf < 4; ++nf)
        acc[4 + mf][nf] = __builtin_amdgcn_mfma_f32_16x16x32_bf16(a[mf], b[nf],
                                                                  acc[4 + mf][nf], 0, 0, 0);
    __builtin_amdgcn_s_setprio(0);
    asm volatile("s_waitcnt vmcnt(0)" ::: "memory");  // t+1 stages resident
    __builtin_amdgcn_s_barrier();
  }

#pragma unroll
  for (int mf = 0; mf < 8; ++mf) {
    const int row0 = brow + (wave >> 2) * 128 + mf * 16 + fq * 4;
#pragma unroll
    for (int nf = 0; nf < 4; ++nf) {
      const int col = bcol + (wave & 3) * 64 + nf * 16 + fr;
#pragma unroll
      for (int j = 0; j < 4; ++j) {
        const size_t o = (size_t)(row0 + j) * N + col;
        const float vv = acc[mf][nf][j];
        if constexpr (EPI == 0) {
          outB[o] = f2bf(vv);
        } else if constexpr (EPI == 1) {
          outF[o] = vv;
        } else if constexpr (EPI == 2) {
          outF[o] = vv + addF[o];
        } else {
          outB[o] = f2bf(0.5f * vv * (1.0f + erff(vv * 0.70710678118654752f)));
        }
      }
    }
  }
}

// ---------------------------------------------------------------- attention
__global__ __launch_bounds__(256)
void attn_kernel(const u16* __restrict__ q, const u16* __restrict__ k,
                 const u16* __restrict__ v, u16* __restrict__ ao) {
  __shared__ __align__(16) u16 Qs[64 * 64];
  __shared__ __align__(16) u16 Ks[36 * 64];
  __shared__ __align__(16) u16 Vs[36 * 64];
  __shared__ float Ps[64 * 36];
  const int bid = blockIdx.x;
  const int h = bid & 15, qw = (bid >> 4) & 15, b = bid >> 8;
  const int tid = threadIdx.x;
  const size_t qbase = ((size_t)b * 1024) * 1024 + (size_t)h * 64;
  for (int i = tid; i < 64 * 16; i += 256) {
    int l = i >> 4, d4 = (i & 15) * 4;
    *(ushort4*)&Qs[l * 64 + d4] =
        *(const ushort4*)&q[qbase + (size_t)(l * 16 + qw) * 1024 + d4];
  }
  const size_t kvbase = ((size_t)(b * 16 + qw)) * 36 * 1024 + (size_t)h * 64;
  for (int i = tid; i < 36 * 16; i += 256) {
    int w = i >> 4, d4 = (i & 15) * 4;
    *(ushort4*)&Ks[w * 64 + d4] = *(const ushort4*)&k[kvbase + (size_t)w * 1024 + d4];
    *(ushort4*)&Vs[w * 64 + d4] = *(const ushort4*)&v[kvbase + (size_t)w * 1024 + d4];
  }
  __syncthreads();
  const int l = tid >> 2, quad = tid & 3;
  float sc[9];
#pragma unroll
  for (int wi = 0; wi < 9; ++wi) {
    int w = quad * 9 + wi;
    float acc = 0.f;
#pragma unroll
    for (int dd = 0; dd < 64; dd += 4) {
      ushort4 qv = *(const ushort4*)&Qs[l * 64 + dd];
      ushort4 kv = *(const ushort4*)&Ks[w * 64 + dd];
      acc += bf2f(qv.x) * bf2f(kv.x) + bf2f(qv.y) * bf2f(kv.y) +
             bf2f(qv.z) * bf2f(kv.z) + bf2f(qv.w) * bf2f(kv.w);
    }
    sc[wi] = acc * 0.125f;
  }
  float mx = sc[0];
#pragma unroll
  for (int wi = 1; wi < 9; ++wi) mx = fmaxf(mx, sc[wi]);
  mx = fmaxf(mx, __shfl_xor(mx, 1));
  mx = fmaxf(mx, __shfl_xor(mx, 2));
  float sum = 0.f;
#pragma unroll
  for (int wi = 0; wi < 9; ++wi) { sc[wi] = __expf(sc[wi] - mx); sum += sc[wi]; }
  sum += __shfl_xor(sum, 1);
  sum += __shfl_xor(sum, 2);
  const float inv = 1.0f / sum;
#pragma unroll
  for (int wi = 0; wi < 9; ++wi) Ps[l * 36 + quad * 9 + wi] = sc[wi] * inv;
  __syncthreads();
  float o[16];
#pragma unroll
  for (int dd = 0; dd < 16; ++dd) o[dd] = 0.f;
  for (int w = 0; w < 36; ++w) {
    float p = Ps[l * 36 + w];
#pragma unroll
    for (int dd = 0; dd < 16; dd += 4) {
      ushort4 vv = *(const ushort4*)&Vs[w * 64 + quad * 16 + dd];
      o[dd] += p * bf2f(vv.x); o[dd + 1] += p * bf2f(vv.y);
      o[dd + 2] += p * bf2f(vv.z); o[dd + 3] += p * bf2f(vv.w);
    }
  }
  const size_t obase = qbase + (size_t)(l * 16 + qw) * 1024 + quad * 16;
#pragma unroll
  for (int dd = 0; dd < 16; dd += 4) {
    ushort4 ov;
    ov.x = f2bf(o[dd]); ov.y = f2bf(o[dd + 1]);
    ov.z = f2bf(o[dd + 2]); ov.w = f2bf(o[dd + 3]);
    *(ushort4*)&ao[obase + dd] = ov;
  }
}

// ---------------------------------------------------------------- launch
extern "C" void kernel_launch(void* const* d_in, const int* in_sizes, int n_in,
                              void* d_out, int out_size, void* d_ws, size_t ws_size,
                              hipStream_t stream) {
  const float* gctx = (const float*)d_in[1];
  const float* queries = (const float*)d_in[4];
  const float* image_tokens = (const float*)d_in[5];
  const float* W_in = (const float*)d_in[7];
  const float* W_ctx = (const float*)d_in[8];
  const float* ln_q_g = (const float*)d_in[9];
  const float* ln_q_b = (const float*)d_in[10];
  const float* Wq = (const float*)d_in[11];
  const float* ln_k_g = (const float*)d_in[12];
  const float* ln_k_b = (const float*)d_in[13];
  const float* Wk = (const float*)d_in[14];
  const float* ln_v_g = (const float*)d_in[15];
  const float* ln_v_b = (const float*)d_in[16];
  const float* Wv = (const float*)d_in[17];
  const float* Wo = (const float*)d_in[18];
  const float* norm_g = (const float*)d_in[19];
  const float* norm_b = (const float*)d_in[20];
  const float* W1 = (const float*)d_in[21];
  const float* W2 = (const float*)d_in[22];
  float* out = (float*)d_out;

  // ---- workspace arena (136 MiB) ----
  char* ws = (char*)d_ws;
  const size_t MB = 1024 * 1024;
  u16* w_in_b  = (u16*)(ws + 0 * MB);
  u16* w_ctx_b = (u16*)(ws + 4 * MB);
  u16* wq_b    = (u16*)(ws + 6 * MB);
  u16* wk_b    = (u16*)(ws + 8 * MB);
  u16* wv_b    = (u16*)(ws + 10 * MB);
  u16* wo_b    = (u16*)(ws + 12 * MB);
  u16* w1_b    = (u16*)(ws + 14 * MB);
  u16* w2_b    = (u16*)(ws + 16 * MB);
  char* regA = ws + 18 * MB;   // 64 MiB
  char* regB = regA + 64 * MB; // 36 MiB
  char* regC = regB + 36 * MB; // 18 MiB

  u16* acat = (u16*)regA;
  u16* pqln = (u16*)regA;
  u16* qmat = (u16*)(regA + 32 * MB);
  u16* vln  = (u16*)regA;
  u16* aoh  = (u16*)regA;
  u16* xmat = (u16*)(regA + 32 * MB);

  float* winp = (float*)regB;
  u16* kmat = (u16*)regB;
  u16* vmat = (u16*)(regB + 18 * MB);
  u16* gout = (u16*)regB;

  u16* gcb = (u16*)regC;
  u16* kln = (u16*)regC;

  float* pq = out;   // f32 16384x1024, lives in d_out

  Cvt9 jobs;
  const float* srcs[9] = {W_in, W_ctx, Wq, Wk, Wv, Wo, W1, W2, gctx};
  u16* dsts[9] = {w_in_b, w_ctx_b, wq_b, wk_b, wv_b, wo_b, w1_b, w2_b, gcb};
  long sizes[9] = {2048l * 1024, 1048576, 1048576, 1048576, 1048576,
                   1048576, 1048576, 1048576, 9216l * 1024};
  long cum = 0;
  for (int j = 0; j < 9; ++j) {
    jobs.s[j] = srcs[j];
    jobs.d[j] = dsts[j];
    jobs.cumv[j] = cum;
    cum += sizes[j] / 4;
  }
  jobs.cumv[9] = cum;
  convert_batch<<<dim3(2048), dim3(256), 0, stream>>>(jobs);
  build_acat<<<dim3(8192), dim3(256), 0, stream>>>(queries, image_tokens, acat);

  // grids: M=16384 -> 256 blocks; M=9216 -> 144 blocks (both % 8 == 0)
  gemm256<1><<<dim3(256), dim3(512), 0, stream>>>(acat, w_in_b, nullptr, pq,
                                                  nullptr, 16384, 1024, 2048);
  ln_rows<<<dim3(16384), dim3(256), 0, stream>>>(pq, ln_q_g, ln_q_b, pqln);
  gemm256<0><<<dim3(256), dim3(512), 0, stream>>>(pqln, wq_b, qmat, nullptr,
                                                  nullptr, 16384, 1024, 1024);
  gemm256<1><<<dim3(144), dim3(512), 0, stream>>>(gcb, w_ctx_b, nullptr, winp,
                                                  nullptr, 9216, 1024, 1024);
  ln_kv<<<dim3(9216), dim3(256), 0, stream>>>(winp, ln_k_g, ln_k_b, ln_v_g,
                                              ln_v_b, kln, vln);
  gemm256<0><<<dim3(144), dim3(512), 0, stream>>>(kln, wk_b, kmat, nullptr,
                                                  nullptr, 9216, 1024, 1024);
  gemm256<0><<<dim3(144), dim3(512), 0, stream>>>(vln, wv_b, vmat, nullptr,
                                                  nullptr, 9216, 1024, 1024);
  attn_kernel<<<dim3(4096), dim3(256), 0, stream>>>(qmat, kmat, vmat, aoh);
  gemm256<2><<<dim3(256), dim3(512), 0, stream>>>(aoh, wo_b, nullptr, pq, pq,
                                                  16384, 1024, 1024);
  ln_rows<<<dim3(16384), dim3(256), 0, stream>>>(pq, norm_g, norm_b, xmat);
  gemm256<3><<<dim3(256), dim3(512), 0, stream>>>(xmat, w1_b, gout, nullptr,
                                                  nullptr, 16384, 1024, 1024);
  gemm256<2><<<dim3(256), dim3(512), 0, stream>>>(gout, w2_b, nullptr, out,
                                                  image_tokens, 16384, 1024, 1024);
}

// Round 8
// 521.971 us; speedup vs baseline: 1.2157x; 1.0189x over previous
//
#include <hip/hip_runtime.h>
#include <cstdint>
#include <cstddef>

typedef unsigned short u16;
typedef __bf16 bf16_t;
typedef bf16_t bf16x8 __attribute__((ext_vector_type(8)));
typedef float f32x4 __attribute__((ext_vector_type(4)));

#define DEV __device__ __forceinline__
#define AS1 __attribute__((address_space(1)))
#define AS3 __attribute__((address_space(3)))

DEV u16 f2bf(float f) {
  unsigned u = __float_as_uint(f);
  u += 0x7fffu + ((u >> 16) & 1u);
  return (u16)(u >> 16);
}
DEV float bf2f(u16 h) {
  return __uint_as_float(((unsigned)h) << 16);
}

// ---------------------------------------------------------------- converts
struct Cvt9 {
  const float* s[9];
  u16* d[9];
  long cumv[10];
};

__global__ __launch_bounds__(256)
void convert_batch(Cvt9 jobs) {
  const long total = jobs.cumv[9];
  for (long i = (long)blockIdx.x * 256 + threadIdx.x; i < total;
       i += (long)gridDim.x * 256) {
    int j = 0;
#pragma unroll
    for (int t = 0; t < 8; ++t)
      if (i >= jobs.cumv[t + 1]) j = t + 1;
    const long e = (i - jobs.cumv[j]) * 4;
    float4 v = *(const float4*)(jobs.s[j] + e);
    ushort4 o;
    o.x = f2bf(v.x); o.y = f2bf(v.y); o.z = f2bf(v.z); o.w = f2bf(v.w);
    *(ushort4*)(jobs.d[j] + e) = o;
  }
}

__global__ __launch_bounds__(256)
void build_acat(const float* __restrict__ q, const float* __restrict__ it,
                u16* __restrict__ dst) {
  const long total = 16384l * 2048 / 4;
  for (long i = (long)blockIdx.x * 256 + threadIdx.x; i < total;
       i += (long)gridDim.x * 256) {
    long e = i * 4;
    int m = (int)(e >> 11);
    int k = (int)(e & 2047);
    const float* s = (k < 1024) ? (q + (long)m * 1024 + k)
                                : (it + (long)m * 1024 + (k - 1024));
    float4 v = *(const float4*)s;
    ushort4 o;
    o.x = f2bf(v.x); o.y = f2bf(v.y); o.z = f2bf(v.z); o.w = f2bf(v.w);
    *(ushort4*)(dst + e) = o;
  }
}

// ---------------------------------------------------------------- layernorm
__global__ __launch_bounds__(256)
void ln_rows(const float* __restrict__ x, const float* __restrict__ g,
             const float* __restrict__ b, u16* __restrict__ out) {
  __shared__ float red[8];
  const int row = blockIdx.x, tid = threadIdx.x;
  const float* xr = x + (size_t)row * 1024;
  float4 v = *(const float4*)(xr + tid * 4);
  float s = v.x + v.y + v.z + v.w;
  float ss = v.x * v.x + v.y * v.y + v.z * v.z + v.w * v.w;
#pragma unroll
  for (int o = 32; o > 0; o >>= 1) { s += __shfl_xor(s, o); ss += __shfl_xor(ss, o); }
  if ((tid & 63) == 0) { red[tid >> 6] = s; red[4 + (tid >> 6)] = ss; }
  __syncthreads();
  s = red[0] + red[1] + red[2] + red[3];
  ss = red[4] + red[5] + red[6] + red[7];
  const float mean = s * 0.0009765625f;
  const float var = ss * 0.0009765625f - mean * mean;
  const float rinv = rsqrtf(var + 1e-5f);
  const int c = tid * 4;
  float4 gg = *(const float4*)(g + c);
  float4 bb = *(const float4*)(b + c);
  ushort4 o4;
  o4.x = f2bf((v.x - mean) * rinv * gg.x + bb.x);
  o4.y = f2bf((v.y - mean) * rinv * gg.y + bb.y);
  o4.z = f2bf((v.z - mean) * rinv * gg.z + bb.z);
  o4.w = f2bf((v.w - mean) * rinv * gg.w + bb.w);
  *(ushort4*)(out + (size_t)row * 1024 + c) = o4;
}

__global__ __launch_bounds__(256)
void ln_kv(const float* __restrict__ winp,
           const float* __restrict__ gk, const float* __restrict__ bk,
           const float* __restrict__ gv, const float* __restrict__ bv,
           u16* __restrict__ kout, u16* __restrict__ vout) {
  __shared__ float red[8];
  const int m = blockIdx.x, tid = threadIdx.x;
  const int b = m / 576, rem = m % 576;
  const int qw = rem / 36, w = rem % 36;
  const int gidx = (qw >> 2) * 144 + (w / 6) * 24 + (qw & 3) * 6 + (w % 6);
  const float* xr = winp + ((size_t)b * 576 + gidx) * 1024;
  float4 v = *(const float4*)(xr + tid * 4);
  float s = v.x + v.y + v.z + v.w;
  float ss = v.x * v.x + v.y * v.y + v.z * v.z + v.w * v.w;
#pragma unroll
  for (int o = 32; o > 0; o >>= 1) { s += __shfl_xor(s, o); ss += __shfl_xor(ss, o); }
  if ((tid & 63) == 0) { red[tid >> 6] = s; red[4 + (tid >> 6)] = ss; }
  __syncthreads();
  s = red[0] + red[1] + red[2] + red[3];
  ss = red[4] + red[5] + red[6] + red[7];
  const float mean = s * 0.0009765625f;
  const float var = ss * 0.0009765625f - mean * mean;
  const float rinv = rsqrtf(var + 1e-5f);
  const int c = tid * 4;
  float4 gg = *(const float4*)(gk + c);
  float4 bb = *(const float4*)(bk + c);
  float4 g2 = *(const float4*)(gv + c);
  float4 b2 = *(const float4*)(bv + c);
  float nx = (v.x - mean) * rinv, ny = (v.y - mean) * rinv;
  float nz = (v.z - mean) * rinv, nw = (v.w - mean) * rinv;
  ushort4 ok, ov;
  ok.x = f2bf(nx * gg.x + bb.x); ok.y = f2bf(ny * gg.y + bb.y);
  ok.z = f2bf(nz * gg.z + bb.z); ok.w = f2bf(nw * gg.w + bb.w);
  ov.x = f2bf(nx * g2.x + b2.x); ov.y = f2bf(ny * g2.y + b2.y);
  ov.z = f2bf(nz * g2.z + b2.z); ov.w = f2bf(nw * g2.w + b2.w);
  *(ushort4*)(kout + (size_t)m * 1024 + c) = ok;
  *(ushort4*)(vout + (size_t)m * 1024 + c) = ov;
}

// ---------------------------------------------------------------- GEMM 256x256
// C[M,N] = A[M,K] * B[N,K]^T  (bf16 in, fp32 acc).  N == 1024, K % 64 == 0.
// 512 thr / 8 waves (2M x 4N), per-wave 128x64.  BK=64, 2 K-tile LDS buffers.
// Quarter-pipelined K-tile (overlap LDS reads with MFMA): quarters
// (ks,mh) = q0(0,0) q1(0,1) q2(1,0) q3(1,1); quarter q+1's ds_reads are
// issued BEFORE quarter q's 16-MFMA cluster (double-buffered frag sets
// a0/a1, b0/b1).  ONE __syncthreads per K-tile (its vmcnt(0)/lgkm(0) drain
// publishes the staged next tile and closes the LDS WAR window).  Compiler
// inserts counted lgkmcnt waits from register deps; sched_barrier(0) pins
// the read/MFMA interleave.  Staging issued early in the tile -> drain free.
// Bank swizzle (verified 0 conflicts): LDS slot(row,s) = global chunk
// s ^ (row&7); stage side inverse-permutes the GLOBAL column, read side XORs.
// EPI: 0 = bf16 store, 1 = f32 store, 2 = f32 acc+addF, 3 = gelu->bf16
template <int EPI>
__global__ __launch_bounds__(512, 2)
void gemm256(const u16* __restrict__ A, const u16* __restrict__ Bw,
             u16* __restrict__ outB, float* __restrict__ outF,
             const float* __restrict__ addF, int M, int N, int K) {
  __shared__ __align__(16) u16 lds[2][2][16384];  // [buf][A/B][256 rows x 64 k]
  const int tid = threadIdx.x;
  const int wave = tid >> 6, lane = tid & 63;
  const int fr = lane & 15, fq = lane >> 4;
  // XCD-chunked swizzle (grids 256 / 144, both % 8 == 0)
  const int swz = (blockIdx.x & 7) * ((int)gridDim.x >> 3) + (blockIdx.x >> 3);
  const int brow = (swz >> 2) << 8;   // N=1024 -> 4 col tiles
  const int bcol = (swz & 3) << 8;

  // staging: thread -> (row = tid>>3 (+64i), chunk = tid&7), LDS dest linear
  const int srow = tid >> 3;
  const int cgo = ((tid & 7) ^ (srow & 7)) << 3;   // inverse-swizzled global col
  const u16* pa0 = A + (size_t)(brow + srow) * K + cgo;
  const u16* pb0 = Bw + (size_t)(bcol + srow) * K + cgo;
  const size_t rstep = (size_t)64 * K;

  f32x4 acc[8][4];
#pragma unroll
  for (int mf = 0; mf < 8; ++mf)
#pragma unroll
    for (int nf = 0; nf < 4; ++nf) acc[mf][nf] = (f32x4){0.f, 0.f, 0.f, 0.f};

  const int fx = fr & 7;
  const int arow = (wave >> 2) * 128 + fr;   // + mh*64 + mf*16
  const int brl = (wave & 3) * 64 + fr;      // + nf*16
  const int ck0 = (fq ^ fx) << 3;            // swizzled chunk, ks=0
  const int ck1 = ((4 + fq) ^ fx) << 3;      // swizzled chunk, ks=1

  auto STAGE_A = [&](int buf, int kt) {
    const int k0 = kt << 6;
#pragma unroll
    for (int i = 0; i < 4; ++i)
      __builtin_amdgcn_global_load_lds((const AS1 void*)(pa0 + i * rstep + k0),
                                       (AS3 void*)&lds[buf][0][i * 4096 + tid * 8],
                                       16, 0, 0);
  };
  auto STAGE_B = [&](int buf, int kt) {
    const int k0 = kt << 6;
#pragma unroll
    for (int i = 0; i < 4; ++i)
      __builtin_amdgcn_global_load_lds((const AS1 void*)(pb0 + i * rstep + k0),
                                       (AS3 void*)&lds[buf][1][i * 4096 + tid * 8],
                                       16, 0, 0);
  };

  const int NT = K >> 6;
  STAGE_A(0, 0);
  STAGE_B(0, 0);
  __syncthreads();   // drains vmcnt(0): buf0 published

  bf16x8 a0[4], a1[4], b0[4], b1[4];
  for (int t = 0; t < NT; ++t) {
    const u16* la = &lds[t & 1][0][0];
    const u16* lb = &lds[t & 1][1][0];
    const int nxt = (t + 1) & 1;

    // Q0 reads (b0 + a0 : ks0,mh0) and Q1 reads (a1 : ks0,mh1) issued up front
#pragma unroll
    for (int nf = 0; nf < 4; ++nf)
      b0[nf] = *(const bf16x8*)&lb[(brl + nf * 16) * 64 + ck0];
#pragma unroll
    for (int mf = 0; mf < 4; ++mf)
      a0[mf] = *(const bf16x8*)&la[(arow + mf * 16) * 64 + ck0];
#pragma unroll
    for (int mf = 0; mf < 4; ++mf)
      a1[mf] = *(const bf16x8*)&la[(arow + 64 + mf * 16) * 64 + ck0];
    if (t + 1 < NT) STAGE_A(nxt, t + 1);
    __builtin_amdgcn_sched_barrier(0);
    // MFMA Q0 (needs b0,a0; a1 + stage still in flight)
    __builtin_amdgcn_s_setprio(1);
#pragma unroll
    for (int mf = 0; mf < 4; ++mf)
#pragma unroll
      for (int nf = 0; nf < 4; ++nf)
        acc[mf][nf] = __builtin_amdgcn_mfma_f32_16x16x32_bf16(a0[mf], b0[nf],
                                                              acc[mf][nf], 0, 0, 0);
    __builtin_amdgcn_s_setprio(0);
    // Q2 reads (b1 + a0 : ks1,mh0) issued before MFMA Q1
#pragma unroll
    for (int nf = 0; nf < 4; ++nf)
      b1[nf] = *(const bf16x8*)&lb[(brl + nf * 16) * 64 + ck1];
#pragma unroll
    for (int mf = 0; mf < 4; ++mf)
      a0[mf] = *(const bf16x8*)&la[(arow + mf * 16) * 64 + ck1];
    __builtin_amdgcn_sched_barrier(0);
    __builtin_amdgcn_s_setprio(1);
#pragma unroll
    for (int mf = 0; mf < 4; ++mf)
#pragma unroll
      for (int nf = 0; nf < 4; ++nf)
        acc[4 + mf][nf] = __builtin_amdgcn_mfma_f32_16x16x32_bf16(a1[mf], b0[nf],
                                                                  acc[4 + mf][nf], 0, 0, 0);
    __builtin_amdgcn_s_setprio(0);
    // Q3 reads (a1 : ks1,mh1) + STAGE_B before MFMA Q2
#pragma unroll
    for (int mf = 0; mf < 4; ++mf)
      a1[mf] = *(const bf16x8*)&la[(arow + 64 + mf * 16) * 64 + ck1];
    if (t + 1 < NT) STAGE_B(nxt, t + 1);
    __builtin_amdgcn_sched_barrier(0);
    __builtin_amdgcn_s_setprio(1);
#pragma unroll
    for (int mf = 0; mf < 4; ++mf)
#pragma unroll
      for (int nf = 0; nf < 4; ++nf)
        acc[mf][nf] = __builtin_amdgcn_mfma_f32_16x16x32_bf16(a0[mf], b1[nf],
                                                              acc[mf][nf], 0, 0, 0);
    __builtin_amdgcn_s_setprio(0);
    __builtin_amdgcn_sched_barrier(0);
    __builtin_amdgcn_s_setprio(1);
#pragma unroll
    for (int mf = 0; mf < 4; ++mf)
#pragma unroll
      for (int nf = 0; nf < 4; ++nf)
        acc[4 + mf][nf] = __builtin_amdgcn_mfma_f32_16x16x32_bf16(a1[mf], b1[nf],
                                                                  acc[4 + mf][nf], 0, 0, 0);
    __builtin_amdgcn_s_setprio(0);
    // single per-tile barrier: drains vmcnt(0)/lgkm(0), publishes staged tile,
    // closes the WAR window for next tile's staging.
    __syncthreads();
  }

#pragma unroll
  for (int mf = 0; mf < 8; ++mf) {
    const int row0 = brow + (wave >> 2) * 128 + mf * 16 + fq * 4;
#pragma unroll
    for (int nf = 0; nf < 4; ++nf) {
      const int col = bcol + (wave & 3) * 64 + nf * 16 + fr;
#pragma unroll
      for (int j = 0; j < 4; ++j) {
        const size_t o = (size_t)(row0 + j) * N + col;
        const float vv = acc[mf][nf][j];
        if constexpr (EPI == 0) {
          outB[o] = f2bf(vv);
        } else if constexpr (EPI == 1) {
          outF[o] = vv;
        } else if constexpr (EPI == 2) {
          outF[o] = vv + addF[o];
        } else {
          outB[o] = f2bf(0.5f * vv * (1.0f + erff(vv * 0.70710678118654752f)));
        }
      }
    }
  }
}

// ---------------------------------------------------------------- attention
__global__ __launch_bounds__(256)
void attn_kernel(const u16* __restrict__ q, const u16* __restrict__ k,
                 const u16* __restrict__ v, u16* __restrict__ ao) {
  __shared__ __align__(16) u16 Qs[64 * 64];
  __shared__ __align__(16) u16 Ks[36 * 64];
  __shared__ __align__(16) u16 Vs[36 * 64];
  __shared__ float Ps[64 * 36];
  const int bid = blockIdx.x;
  const int h = bid & 15, qw = (bid >> 4) & 15, b = bid >> 8;
  const int tid = threadIdx.x;
  const size_t qbase = ((size_t)b * 1024) * 1024 + (size_t)h * 64;
  for (int i = tid; i < 64 * 16; i += 256) {
    int l = i >> 4, d4 = (i & 15) * 4;
    *(ushort4*)&Qs[l * 64 + d4] =
        *(const ushort4*)&q[qbase + (size_t)(l * 16 + qw) * 1024 + d4];
  }
  const size_t kvbase = ((size_t)(b * 16 + qw)) * 36 * 1024 + (size_t)h * 64;
  for (int i = tid; i < 36 * 16; i += 256) {
    int w = i >> 4, d4 = (i & 15) * 4;
    *(ushort4*)&Ks[w * 64 + d4] = *(const ushort4*)&k[kvbase + (size_t)w * 1024 + d4];
    *(ushort4*)&Vs[w * 64 + d4] = *(const ushort4*)&v[kvbase + (size_t)w * 1024 + d4];
  }
  __syncthreads();
  const int l = tid >> 2, quad = tid & 3;
  float sc[9];
#pragma unroll
  for (int wi = 0; wi < 9; ++wi) {
    int w = quad * 9 + wi;
    float acc = 0.f;
#pragma unroll
    for (int dd = 0; dd < 64; dd += 4) {
      ushort4 qv = *(const ushort4*)&Qs[l * 64 + dd];
      ushort4 kv = *(const ushort4*)&Ks[w * 64 + dd];
      acc += bf2f(qv.x) * bf2f(kv.x) + bf2f(qv.y) * bf2f(kv.y) +
             bf2f(qv.z) * bf2f(kv.z) + bf2f(qv.w) * bf2f(kv.w);
    }
    sc[wi] = acc * 0.125f;
  }
  float mx = sc[0];
#pragma unroll
  for (int wi = 1; wi < 9; ++wi) mx = fmaxf(mx, sc[wi]);
  mx = fmaxf(mx, __shfl_xor(mx, 1));
  mx = fmaxf(mx, __shfl_xor(mx, 2));
  float sum = 0.f;
#pragma unroll
  for (int wi = 0; wi < 9; ++wi) { sc[wi] = __expf(sc[wi] - mx); sum += sc[wi]; }
  sum += __shfl_xor(sum, 1);
  sum += __shfl_xor(sum, 2);
  const float inv = 1.0f / sum;
#pragma unroll
  for (int wi = 0; wi < 9; ++wi) Ps[l * 36 + quad * 9 + wi] = sc[wi] * inv;
  __syncthreads();
  float o[16];
#pragma unroll
  for (int dd = 0; dd < 16; ++dd) o[dd] = 0.f;
  for (int w = 0; w < 36; ++w) {
    float p = Ps[l * 36 + w];
#pragma unroll
    for (int dd = 0; dd < 16; dd += 4) {
      ushort4 vv = *(const ushort4*)&Vs[w * 64 + quad * 16 + dd];
      o[dd] += p * bf2f(vv.x); o[dd + 1] += p * bf2f(vv.y);
      o[dd + 2] += p * bf2f(vv.z); o[dd + 3] += p * bf2f(vv.w);
    }
  }
  const size_t obase = qbase + (size_t)(l * 16 + qw) * 1024 + quad * 16;
#pragma unroll
  for (int dd = 0; dd < 16; dd += 4) {
    ushort4 ov;
    ov.x = f2bf(o[dd]); ov.y = f2bf(o[dd + 1]);
    ov.z = f2bf(o[dd + 2]); ov.w = f2bf(o[dd + 3]);
    *(ushort4*)&ao[obase + dd] = ov;
  }
}

// ---------------------------------------------------------------- launch
extern "C" void kernel_launch(void* const* d_in, const int* in_sizes, int n_in,
                              void* d_out, int out_size, void* d_ws, size_t ws_size,
                              hipStream_t stream) {
  const float* gctx = (const float*)d_in[1];
  const float* queries = (const float*)d_in[4];
  const float* image_tokens = (const float*)d_in[5];
  const float* W_in = (const float*)d_in[7];
  const float* W_ctx = (const float*)d_in[8];
  const float* ln_q_g = (const float*)d_in[9];
  const float* ln_q_b = (const float*)d_in[10];
  const float* Wq = (const float*)d_in[11];
  const float* ln_k_g = (const float*)d_in[12];
  const float* ln_k_b = (const float*)d_in[13];
  const float* Wk = (const float*)d_in[14];
  const float* ln_v_g = (const float*)d_in[15];
  const float* ln_v_b = (const float*)d_in[16];
  const float* Wv = (const float*)d_in[17];
  const float* Wo = (const float*)d_in[18];
  const float* norm_g = (const float*)d_in[19];
  const float* norm_b = (const float*)d_in[20];
  const float* W1 = (const float*)d_in[21];
  const float* W2 = (const float*)d_in[22];
  float* out = (float*)d_out;

  // ---- workspace arena (136 MiB) ----
  char* ws = (char*)d_ws;
  const size_t MB = 1024 * 1024;
  u16* w_in_b  = (u16*)(ws + 0 * MB);
  u16* w_ctx_b = (u16*)(ws + 4 * MB);
  u16* wq_b    = (u16*)(ws + 6 * MB);
  u16* wk_b    = (u16*)(ws + 8 * MB);
  u16* wv_b    = (u16*)(ws + 10 * MB);
  u16* wo_b    = (u16*)(ws + 12 * MB);
  u16* w1_b    = (u16*)(ws + 14 * MB);
  u16* w2_b    = (u16*)(ws + 16 * MB);
  char* regA = ws + 18 * MB;   // 64 MiB
  char* regB = regA + 64 * MB; // 36 MiB
  char* regC = regB + 36 * MB; // 18 MiB

  u16* acat = (u16*)regA;
  u16* pqln = (u16*)regA;
  u16* qmat = (u16*)(regA + 32 * MB);
  u16* vln  = (u16*)regA;
  u16* aoh  = (u16*)regA;
  u16* xmat = (u16*)(regA + 32 * MB);

  float* winp = (float*)regB;
  u16* kmat = (u16*)regB;
  u16* vmat = (u16*)(regB + 18 * MB);
  u16* gout = (u16*)regB;

  u16* gcb = (u16*)regC;
  u16* kln = (u16*)regC;

  float* pq = out;   // f32 16384x1024, lives in d_out

  Cvt9 jobs;
  const float* srcs[9] = {W_in, W_ctx, Wq, Wk, Wv, Wo, W1, W2, gctx};
  u16* dsts[9] = {w_in_b, w_ctx_b, wq_b, wk_b, wv_b, wo_b, w1_b, w2_b, gcb};
  long sizes[9] = {2048l * 1024, 1048576, 1048576, 1048576, 1048576,
                   1048576, 1048576, 1048576, 9216l * 1024};
  long cum = 0;
  for (int j = 0; j < 9; ++j) {
    jobs.s[j] = srcs[j];
    jobs.d[j] = dsts[j];
    jobs.cumv[j] = cum;
    cum += sizes[j] / 4;
  }
  jobs.cumv[9] = cum;
  convert_batch<<<dim3(2048), dim3(256), 0, stream>>>(jobs);
  build_acat<<<dim3(8192), dim3(256), 0, stream>>>(queries, image_tokens, acat);

  // grids: M=16384 -> 256 blocks; M=9216 -> 144 blocks (both % 8 == 0)
  gemm256<1><<<dim3(256), dim3(512), 0, stream>>>(acat, w_in_b, nullptr, pq,
                                                  nullptr, 16384, 1024, 2048);
  ln_rows<<<dim3(16384), dim3(256), 0, stream>>>(pq, ln_q_g, ln_q_b, pqln);
  gemm256<0><<<dim3(256), dim3(512), 0, stream>>>(pqln, wq_b, qmat, nullptr,
                                                  nullptr, 16384, 1024, 1024);
  gemm256<1><<<dim3(144), dim3(512), 0, stream>>>(gcb, w_ctx_b, nullptr, winp,
                                                  nullptr, 9216, 1024, 1024);
  ln_kv<<<dim3(9216), dim3(256), 0, stream>>>(winp, ln_k_g, ln_k_b, ln_v_g,
                                              ln_v_b, kln, vln);
  gemm256<0><<<dim3(144), dim3(512), 0, stream>>>(kln, wk_b, kmat, nullptr,
                                                  nullptr, 9216, 1024, 1024);
  gemm256<0><<<dim3(144), dim3(512), 0, stream>>>(vln, wv_b, vmat, nullptr,
                                                  nullptr, 9216, 1024, 1024);
  attn_kernel<<<dim3(4096), dim3(256), 0, stream>>>(qmat, kmat, vmat, aoh);
  gemm256<2><<<dim3(256), dim3(512), 0, stream>>>(aoh, wo_b, nullptr, pq, pq,
                                                  16384, 1024, 1024);
  ln_rows<<<dim3(16384), dim3(256), 0, stream>>>(pq, norm_g, norm_b, xmat);
  gemm256<3><<<dim3(256), dim3(512), 0, stream>>>(xmat, w1_b, gout, nullptr,
                                                  nullptr, 16384, 1024, 1024);
  gemm256<2><<<dim3(256), dim3(512), 0, stream>>>(gout, w2_b, nullptr, out,
                                                  image_tokens, 16384, 1024, 1024);
}

// Round 9
// 498.568 us; speedup vs baseline: 1.2728x; 1.0469x over previous
//
#include <hip/hip_runtime.h>
#include <cstdint>
#include <cstddef>

typedef unsigned short u16;
typedef __bf16 bf16_t;
typedef bf16_t bf16x8 __attribute__((ext_vector_type(8)));
typedef float f32x4 __attribute__((ext_vector_type(4)));

#define DEV __device__ __forceinline__
#define AS1 __attribute__((address_space(1)))
#define AS3 __attribute__((address_space(3)))

DEV u16 f2bf(float f) {
  unsigned u = __float_as_uint(f);
  u += 0x7fffu + ((u >> 16) & 1u);
  return (u16)(u >> 16);
}
DEV float bf2f(u16 h) {
  return __uint_as_float(((unsigned)h) << 16);
}

// ---------------------------------------------------------------- converts
struct Cvt9 {
  const float* s[9];
  u16* d[9];
  long cumv[10];
};

__global__ __launch_bounds__(256)
void convert_batch(Cvt9 jobs) {
  const long total = jobs.cumv[9];
  for (long i = (long)blockIdx.x * 256 + threadIdx.x; i < total;
       i += (long)gridDim.x * 256) {
    int j = 0;
#pragma unroll
    for (int t = 0; t < 8; ++t)
      if (i >= jobs.cumv[t + 1]) j = t + 1;
    const long e = (i - jobs.cumv[j]) * 4;
    float4 v = *(const float4*)(jobs.s[j] + e);
    ushort4 o;
    o.x = f2bf(v.x); o.y = f2bf(v.y); o.z = f2bf(v.z); o.w = f2bf(v.w);
    *(ushort4*)(jobs.d[j] + e) = o;
  }
}

__global__ __launch_bounds__(256)
void build_acat(const float* __restrict__ q, const float* __restrict__ it,
                u16* __restrict__ dst) {
  const long total = 16384l * 2048 / 4;
  for (long i = (long)blockIdx.x * 256 + threadIdx.x; i < total;
       i += (long)gridDim.x * 256) {
    long e = i * 4;
    int m = (int)(e >> 11);
    int k = (int)(e & 2047);
    const float* s = (k < 1024) ? (q + (long)m * 1024 + k)
                                : (it + (long)m * 1024 + (k - 1024));
    float4 v = *(const float4*)s;
    ushort4 o;
    o.x = f2bf(v.x); o.y = f2bf(v.y); o.z = f2bf(v.z); o.w = f2bf(v.w);
    *(ushort4*)(dst + e) = o;
  }
}

// ---------------------------------------------------------------- layernorm
__global__ __launch_bounds__(256)
void ln_rows(const float* __restrict__ x, const float* __restrict__ g,
             const float* __restrict__ b, u16* __restrict__ out) {
  __shared__ float red[8];
  const int row = blockIdx.x, tid = threadIdx.x;
  const float* xr = x + (size_t)row * 1024;
  float4 v = *(const float4*)(xr + tid * 4);
  float s = v.x + v.y + v.z + v.w;
  float ss = v.x * v.x + v.y * v.y + v.z * v.z + v.w * v.w;
#pragma unroll
  for (int o = 32; o > 0; o >>= 1) { s += __shfl_xor(s, o); ss += __shfl_xor(ss, o); }
  if ((tid & 63) == 0) { red[tid >> 6] = s; red[4 + (tid >> 6)] = ss; }
  __syncthreads();
  s = red[0] + red[1] + red[2] + red[3];
  ss = red[4] + red[5] + red[6] + red[7];
  const float mean = s * 0.0009765625f;
  const float var = ss * 0.0009765625f - mean * mean;
  const float rinv = rsqrtf(var + 1e-5f);
  const int c = tid * 4;
  float4 gg = *(const float4*)(g + c);
  float4 bb = *(const float4*)(b + c);
  ushort4 o4;
  o4.x = f2bf((v.x - mean) * rinv * gg.x + bb.x);
  o4.y = f2bf((v.y - mean) * rinv * gg.y + bb.y);
  o4.z = f2bf((v.z - mean) * rinv * gg.z + bb.z);
  o4.w = f2bf((v.w - mean) * rinv * gg.w + bb.w);
  *(ushort4*)(out + (size_t)row * 1024 + c) = o4;
}

__global__ __launch_bounds__(256)
void ln_kv(const float* __restrict__ winp,
           const float* __restrict__ gk, const float* __restrict__ bk,
           const float* __restrict__ gv, const float* __restrict__ bv,
           u16* __restrict__ kout, u16* __restrict__ vout) {
  __shared__ float red[8];
  const int m = blockIdx.x, tid = threadIdx.x;
  const int b = m / 576, rem = m % 576;
  const int qw = rem / 36, w = rem % 36;
  const int gidx = (qw >> 2) * 144 + (w / 6) * 24 + (qw & 3) * 6 + (w % 6);
  const float* xr = winp + ((size_t)b * 576 + gidx) * 1024;
  float4 v = *(const float4*)(xr + tid * 4);
  float s = v.x + v.y + v.z + v.w;
  float ss = v.x * v.x + v.y * v.y + v.z * v.z + v.w * v.w;
#pragma unroll
  for (int o = 32; o > 0; o >>= 1) { s += __shfl_xor(s, o); ss += __shfl_xor(ss, o); }
  if ((tid & 63) == 0) { red[tid >> 6] = s; red[4 + (tid >> 6)] = ss; }
  __syncthreads();
  s = red[0] + red[1] + red[2] + red[3];
  ss = red[4] + red[5] + red[6] + red[7];
  const float mean = s * 0.0009765625f;
  const float var = ss * 0.0009765625f - mean * mean;
  const float rinv = rsqrtf(var + 1e-5f);
  const int c = tid * 4;
  float4 gg = *(const float4*)(gk + c);
  float4 bb = *(const float4*)(bk + c);
  float4 g2 = *(const float4*)(gv + c);
  float4 b2 = *(const float4*)(bv + c);
  float nx = (v.x - mean) * rinv, ny = (v.y - mean) * rinv;
  float nz = (v.z - mean) * rinv, nw = (v.w - mean) * rinv;
  ushort4 ok, ov;
  ok.x = f2bf(nx * gg.x + bb.x); ok.y = f2bf(ny * gg.y + bb.y);
  ok.z = f2bf(nz * gg.z + bb.z); ok.w = f2bf(nw * gg.w + bb.w);
  ov.x = f2bf(nx * g2.x + b2.x); ov.y = f2bf(ny * g2.y + b2.y);
  ov.z = f2bf(nz * g2.z + b2.z); ov.w = f2bf(nw * g2.w + b2.w);
  *(ushort4*)(kout + (size_t)m * 1024 + c) = ok;
  *(ushort4*)(vout + (size_t)m * 1024 + c) = ov;
}

// ---------------------------------------------------------------- GEMM 256x256
// (unchanged quarter-pipelined kernel; see round 7 notes)
// EPI: 0 bf16, 1 f32, 2 f32 acc+addF, 3 gelu->bf16,
//      4 bf16 scattered V^T layout: vt[bqw][col][w] (bqw=row/36, w=row%36)
template <int EPI>
__global__ __launch_bounds__(512, 2)
void gemm256(const u16* __restrict__ A, const u16* __restrict__ Bw,
             u16* __restrict__ outB, float* __restrict__ outF,
             const float* __restrict__ addF, int M, int N, int K) {
  __shared__ __align__(16) u16 lds[2][2][16384];  // [buf][A/B][256 rows x 64 k]
  const int tid = threadIdx.x;
  const int wave = tid >> 6, lane = tid & 63;
  const int fr = lane & 15, fq = lane >> 4;
  const int swz = (blockIdx.x & 7) * ((int)gridDim.x >> 3) + (blockIdx.x >> 3);
  const int brow = (swz >> 2) << 8;   // N=1024 -> 4 col tiles
  const int bcol = (swz & 3) << 8;

  const int srow = tid >> 3;
  const int cgo = ((tid & 7) ^ (srow & 7)) << 3;   // inverse-swizzled global col
  const u16* pa0 = A + (size_t)(brow + srow) * K + cgo;
  const u16* pb0 = Bw + (size_t)(bcol + srow) * K + cgo;
  const size_t rstep = (size_t)64 * K;

  f32x4 acc[8][4];
#pragma unroll
  for (int mf = 0; mf < 8; ++mf)
#pragma unroll
    for (int nf = 0; nf < 4; ++nf) acc[mf][nf] = (f32x4){0.f, 0.f, 0.f, 0.f};

  const int fx = fr & 7;
  const int arow = (wave >> 2) * 128 + fr;
  const int brl = (wave & 3) * 64 + fr;
  const int ck0 = (fq ^ fx) << 3;
  const int ck1 = ((4 + fq) ^ fx) << 3;

  auto STAGE_A = [&](int buf, int kt) {
    const int k0 = kt << 6;
#pragma unroll
    for (int i = 0; i < 4; ++i)
      __builtin_amdgcn_global_load_lds((const AS1 void*)(pa0 + i * rstep + k0),
                                       (AS3 void*)&lds[buf][0][i * 4096 + tid * 8],
                                       16, 0, 0);
  };
  auto STAGE_B = [&](int buf, int kt) {
    const int k0 = kt << 6;
#pragma unroll
    for (int i = 0; i < 4; ++i)
      __builtin_amdgcn_global_load_lds((const AS1 void*)(pb0 + i * rstep + k0),
                                       (AS3 void*)&lds[buf][1][i * 4096 + tid * 8],
                                       16, 0, 0);
  };

  const int NT = K >> 6;
  STAGE_A(0, 0);
  STAGE_B(0, 0);
  __syncthreads();

  bf16x8 a0[4], a1[4], b0[4], b1[4];
  for (int t = 0; t < NT; ++t) {
    const u16* la = &lds[t & 1][0][0];
    const u16* lb = &lds[t & 1][1][0];
    const int nxt = (t + 1) & 1;

#pragma unroll
    for (int nf = 0; nf < 4; ++nf)
      b0[nf] = *(const bf16x8*)&lb[(brl + nf * 16) * 64 + ck0];
#pragma unroll
    for (int mf = 0; mf < 4; ++mf)
      a0[mf] = *(const bf16x8*)&la[(arow + mf * 16) * 64 + ck0];
#pragma unroll
    for (int mf = 0; mf < 4; ++mf)
      a1[mf] = *(const bf16x8*)&la[(arow + 64 + mf * 16) * 64 + ck0];
    if (t + 1 < NT) STAGE_A(nxt, t + 1);
    __builtin_amdgcn_sched_barrier(0);
    __builtin_amdgcn_s_setprio(1);
#pragma unroll
    for (int mf = 0; mf < 4; ++mf)
#pragma unroll
      for (int nf = 0; nf < 4; ++nf)
        acc[mf][nf] = __builtin_amdgcn_mfma_f32_16x16x32_bf16(a0[mf], b0[nf],
                                                              acc[mf][nf], 0, 0, 0);
    __builtin_amdgcn_s_setprio(0);
#pragma unroll
    for (int nf = 0; nf < 4; ++nf)
      b1[nf] = *(const bf16x8*)&lb[(brl + nf * 16) * 64 + ck1];
#pragma unroll
    for (int mf = 0; mf < 4; ++mf)
      a0[mf] = *(const bf16x8*)&la[(arow + mf * 16) * 64 + ck1];
    __builtin_amdgcn_sched_barrier(0);
    __builtin_amdgcn_s_setprio(1);
#pragma unroll
    for (int mf = 0; mf < 4; ++mf)
#pragma unroll
      for (int nf = 0; nf < 4; ++nf)
        acc[4 + mf][nf] = __builtin_amdgcn_mfma_f32_16x16x32_bf16(a1[mf], b0[nf],
                                                                  acc[4 + mf][nf], 0, 0, 0);
    __builtin_amdgcn_s_setprio(0);
#pragma unroll
    for (int mf = 0; mf < 4; ++mf)
      a1[mf] = *(const bf16x8*)&la[(arow + 64 + mf * 16) * 64 + ck1];
    if (t + 1 < NT) STAGE_B(nxt, t + 1);
    __builtin_amdgcn_sched_barrier(0);
    __builtin_amdgcn_s_setprio(1);
#pragma unroll
    for (int mf = 0; mf < 4; ++mf)
#pragma unroll
      for (int nf = 0; nf < 4; ++nf)
        acc[mf][nf] = __builtin_amdgcn_mfma_f32_16x16x32_bf16(a0[mf], b1[nf],
                                                              acc[mf][nf], 0, 0, 0);
    __builtin_amdgcn_s_setprio(0);
    __builtin_amdgcn_sched_barrier(0);
    __builtin_amdgcn_s_setprio(1);
#pragma unroll
    for (int mf = 0; mf < 4; ++mf)
#pragma unroll
      for (int nf = 0; nf < 4; ++nf)
        acc[4 + mf][nf] = __builtin_amdgcn_mfma_f32_16x16x32_bf16(a1[mf], b1[nf],
                                                                  acc[4 + mf][nf], 0, 0, 0);
    __builtin_amdgcn_s_setprio(0);
    __syncthreads();
  }

#pragma unroll
  for (int mf = 0; mf < 8; ++mf) {
    const int row0 = brow + (wave >> 2) * 128 + mf * 16 + fq * 4;
#pragma unroll
    for (int nf = 0; nf < 4; ++nf) {
      const int col = bcol + (wave & 3) * 64 + nf * 16 + fr;
#pragma unroll
      for (int j = 0; j < 4; ++j) {
        const size_t o = (size_t)(row0 + j) * N + col;
        const float vv = acc[mf][nf][j];
        if constexpr (EPI == 0) {
          outB[o] = f2bf(vv);
        } else if constexpr (EPI == 1) {
          outF[o] = vv;
        } else if constexpr (EPI == 2) {
          outF[o] = vv + addF[o];
        } else if constexpr (EPI == 3) {
          outB[o] = f2bf(0.5f * vv * (1.0f + erff(vv * 0.70710678118654752f)));
        } else {
          // V^T scatter: row -> (bqw, w), dst = vt[bqw*36864 + col*36 + w]
          const int gr = row0 + j;
          const int bqw = gr / 36;
          const int wl = gr - bqw * 36;
          outB[(size_t)bqw * 36864 + (size_t)col * 36 + wl] = f2bf(vv);
        }
      }
    }
  }
}

// ---------------------------------------------------------------- attention
// MFMA attention.  One block per (b, qw, h); 4 waves.
// QK^T: S[64 x 48pad] via 16x16x32 (A=Q[m][d], B=K[w][d] -- the proven
// gemm_bt fragment pattern).  Wave-parallel softmax over C-rows via
// shfl_xor{1,2,4,8}.  P -> LDS (stride 72: banks 4m mod 32, conflict-free).
// PV swapped: O^T = V^T x P^T (A=Vt[d][w], B=P[m][w], both row-major-by-K).
// V^T comes pre-transposed from the V-projection GEMM (EPI 4).
__global__ __launch_bounds__(256)
void attn_kernel(const u16* __restrict__ q, const u16* __restrict__ k,
                 const u16* __restrict__ vt, u16* __restrict__ ao) {
  __shared__ __align__(16) u16 Q_lds[64 * 72];
  __shared__ __align__(16) u16 K_lds[48 * 72];
  __shared__ __align__(16) u16 Vt_lds[64 * 72];
  __shared__ __align__(16) u16 P_lds[64 * 72];
  const int bid = blockIdx.x;
  const int h = bid & 15, qw = (bid >> 4) & 15, b = bid >> 8;
  const int tid = threadIdx.x;
  const int wave = tid >> 6, lane = tid & 63;
  const int lq = lane & 15, lk = lane >> 4;

  // ---- staging ----
  const size_t qbase = (size_t)b * 1048576 + (size_t)h * 64;
  for (int i = tid; i < 64 * 16; i += 256) {
    const int l = i >> 4, c4 = (i & 15) * 4;
    *(ushort4*)&Q_lds[l * 72 + c4] =
        *(const ushort4*)&q[qbase + (size_t)(l * 16 + qw) * 1024 + c4];
  }
  const size_t kvbase = (size_t)((b * 16 + qw) * 36) * 1024 + (size_t)h * 64;
  for (int i = tid; i < 36 * 16; i += 256) {
    const int w = i >> 4, c4 = (i & 15) * 4;
    *(ushort4*)&K_lds[w * 72 + c4] = *(const ushort4*)&k[kvbase + (size_t)w * 1024 + c4];
  }
  const size_t vbase = (size_t)(b * 16 + qw) * 36864 + (size_t)h * 2304;
  for (int i = tid; i < 64 * 9; i += 256) {
    const int d = i / 9, w4 = (i - d * 9) * 4;
    *(ushort4*)&Vt_lds[d * 72 + w4] = *(const ushort4*)&vt[vbase + d * 36 + w4];
  }
  const ushort4 z4 = {0, 0, 0, 0};
  for (int i = tid; i < 64 * 7; i += 256) {     // Vt cols 36..63 = 0
    const int d = i / 7, w = 36 + (i - d * 7) * 4;
    *(ushort4*)&Vt_lds[d * 72 + w] = z4;
  }
  for (int i = tid; i < 64 * 4; i += 256) {     // P cols 48..63 = 0
    const int m = i >> 2, w = 48 + (i & 3) * 4;
    *(ushort4*)&P_lds[m * 72 + w] = z4;
  }
  __syncthreads();

  // ---- QK^T: wave owns m-tile [wave*16, wave*16+16) ----
  bf16x8 qa[2];
#pragma unroll
  for (int ks = 0; ks < 2; ++ks)
    qa[ks] = *(const bf16x8*)&Q_lds[(wave * 16 + lq) * 72 + ks * 32 + lk * 8];
  f32x4 accs[3];
#pragma unroll
  for (int nt = 0; nt < 3; ++nt) accs[nt] = (f32x4){0.f, 0.f, 0.f, 0.f};
#pragma unroll
  for (int nt = 0; nt < 3; ++nt)
#pragma unroll
    for (int ks = 0; ks < 2; ++ks) {
      bf16x8 kb = *(const bf16x8*)&K_lds[(nt * 16 + lq) * 72 + ks * 32 + lk * 8];
      accs[nt] = __builtin_amdgcn_mfma_f32_16x16x32_bf16(qa[ks], kb, accs[nt], 0, 0, 0);
    }

  // ---- softmax per C-row (row = lk*4+j; 16 lanes lq share a row) ----
  const bool v2ok = (lq < 4);   // n-tile 2 covers w = 32+lq; valid iff < 36
#pragma unroll
  for (int j = 0; j < 4; ++j) {
    const float s0 = accs[0][j] * 0.125f;
    const float s1 = accs[1][j] * 0.125f;
    const float s2 = v2ok ? accs[2][j] * 0.125f : -1e30f;
    float mx = fmaxf(fmaxf(s0, s1), s2);
    mx = fmaxf(mx, __shfl_xor(mx, 1));
    mx = fmaxf(mx, __shfl_xor(mx, 2));
    mx = fmaxf(mx, __shfl_xor(mx, 4));
    mx = fmaxf(mx, __shfl_xor(mx, 8));
    const float e0 = __expf(s0 - mx);
    const float e1 = __expf(s1 - mx);
    const float e2 = v2ok ? __expf(s2 - mx) : 0.f;
    float sm = e0 + e1 + e2;
    sm += __shfl_xor(sm, 1);
    sm += __shfl_xor(sm, 2);
    sm += __shfl_xor(sm, 4);
    sm += __shfl_xor(sm, 8);
    const float inv = 1.0f / sm;
    const int mrow = wave * 16 + lk * 4 + j;
    P_lds[mrow * 72 + lq] = f2bf(e0 * inv);
    P_lds[mrow * 72 + 16 + lq] = f2bf(e1 * inv);
    P_lds[mrow * 72 + 32 + lq] = f2bf(e2 * inv);
  }
  __syncthreads();

  // ---- PV swapped: O^T = Vt x P^T; wave owns d-tile [wave*16, +16) ----
  bf16x8 va[2];
#pragma unroll
  for (int ks = 0; ks < 2; ++ks)
    va[ks] = *(const bf16x8*)&Vt_lds[(wave * 16 + lq) * 72 + ks * 32 + lk * 8];
  f32x4 acco[4];
#pragma unroll
  for (int nt = 0; nt < 4; ++nt) acco[nt] = (f32x4){0.f, 0.f, 0.f, 0.f};
#pragma unroll
  for (int nt = 0; nt < 4; ++nt)
#pragma unroll
    for (int ks = 0; ks < 2; ++ks) {
      bf16x8 pb = *(const bf16x8*)&P_lds[(nt * 16 + lq) * 72 + ks * 32 + lk * 8];
      acco[nt] = __builtin_amdgcn_mfma_f32_16x16x32_bf16(va[ks], pb, acco[nt], 0, 0, 0);
    }

  // ---- store: C col = m (lq), row = d = wave*16 + lk*4 + j (4 contig d) ----
#pragma unroll
  for (int nt = 0; nt < 4; ++nt) {
    const int m = nt * 16 + lq;
    const int d0 = wave * 16 + lk * 4;
    ushort4 ov;
    ov.x = f2bf(acco[nt][0]); ov.y = f2bf(acco[nt][1]);
    ov.z = f2bf(acco[nt][2]); ov.w = f2bf(acco[nt][3]);
    *(ushort4*)&ao[qbase + (size_t)(m * 16 + qw) * 1024 + d0] = ov;
  }
}

// ---------------------------------------------------------------- launch
extern "C" void kernel_launch(void* const* d_in, const int* in_sizes, int n_in,
                              void* d_out, int out_size, void* d_ws, size_t ws_size,
                              hipStream_t stream) {
  const float* gctx = (const float*)d_in[1];
  const float* queries = (const float*)d_in[4];
  const float* image_tokens = (const float*)d_in[5];
  const float* W_in = (const float*)d_in[7];
  const float* W_ctx = (const float*)d_in[8];
  const float* ln_q_g = (const float*)d_in[9];
  const float* ln_q_b = (const float*)d_in[10];
  const float* Wq = (const float*)d_in[11];
  const float* ln_k_g = (const float*)d_in[12];
  const float* ln_k_b = (const float*)d_in[13];
  const float* Wk = (const float*)d_in[14];
  const float* ln_v_g = (const float*)d_in[15];
  const float* ln_v_b = (const float*)d_in[16];
  const float* Wv = (const float*)d_in[17];
  const float* Wo = (const float*)d_in[18];
  const float* norm_g = (const float*)d_in[19];
  const float* norm_b = (const float*)d_in[20];
  const float* W1 = (const float*)d_in[21];
  const float* W2 = (const float*)d_in[22];
  float* out = (float*)d_out;

  // ---- workspace arena (136 MiB) ----
  char* ws = (char*)d_ws;
  const size_t MB = 1024 * 1024;
  u16* w_in_b  = (u16*)(ws + 0 * MB);
  u16* w_ctx_b = (u16*)(ws + 4 * MB);
  u16* wq_b    = (u16*)(ws + 6 * MB);
  u16* wk_b    = (u16*)(ws + 8 * MB);
  u16* wv_b    = (u16*)(ws + 10 * MB);
  u16* wo_b    = (u16*)(ws + 12 * MB);
  u16* w1_b    = (u16*)(ws + 14 * MB);
  u16* w2_b    = (u16*)(ws + 16 * MB);
  char* regA = ws + 18 * MB;   // 64 MiB
  char* regB = regA + 64 * MB; // 36 MiB
  char* regC = regB + 36 * MB; // 18 MiB

  u16* acat = (u16*)regA;
  u16* pqln = (u16*)regA;
  u16* qmat = (u16*)(regA + 32 * MB);
  u16* vln  = (u16*)regA;
  u16* aoh  = (u16*)regA;
  u16* xmat = (u16*)(regA + 32 * MB);

  float* winp = (float*)regB;
  u16* kmat = (u16*)regB;
  u16* vtmat = (u16*)(regB + 18 * MB);  // V^T layout: [bqw][1024][36]
  u16* gout = (u16*)regB;

  u16* gcb = (u16*)regC;
  u16* kln = (u16*)regC;

  float* pq = out;   // f32 16384x1024, lives in d_out

  Cvt9 jobs;
  const float* srcs[9] = {W_in, W_ctx, Wq, Wk, Wv, Wo, W1, W2, gctx};
  u16* dsts[9] = {w_in_b, w_ctx_b, wq_b, wk_b, wv_b, wo_b, w1_b, w2_b, gcb};
  long sizes[9] = {2048l * 1024, 1048576, 1048576, 1048576, 1048576,
                   1048576, 1048576, 1048576, 9216l * 1024};
  long cum = 0;
  for (int j = 0; j < 9; ++j) {
    jobs.s[j] = srcs[j];
    jobs.d[j] = dsts[j];
    jobs.cumv[j] = cum;
    cum += sizes[j] / 4;
  }
  jobs.cumv[9] = cum;
  convert_batch<<<dim3(2048), dim3(256), 0, stream>>>(jobs);
  build_acat<<<dim3(8192), dim3(256), 0, stream>>>(queries, image_tokens, acat);

  // grids: M=16384 -> 256 blocks; M=9216 -> 144 blocks (both % 8 == 0)
  gemm256<1><<<dim3(256), dim3(512), 0, stream>>>(acat, w_in_b, nullptr, pq,
                                                  nullptr, 16384, 1024, 2048);
  ln_rows<<<dim3(16384), dim3(256), 0, stream>>>(pq, ln_q_g, ln_q_b, pqln);
  gemm256<0><<<dim3(256), dim3(512), 0, stream>>>(pqln, wq_b, qmat, nullptr,
                                                  nullptr, 16384, 1024, 1024);
  gemm256<1><<<dim3(144), dim3(512), 0, stream>>>(gcb, w_ctx_b, nullptr, winp,
                                                  nullptr, 9216, 1024, 1024);
  ln_kv<<<dim3(9216), dim3(256), 0, stream>>>(winp, ln_k_g, ln_k_b, ln_v_g,
                                              ln_v_b, kln, vln);
  gemm256<0><<<dim3(144), dim3(512), 0, stream>>>(kln, wk_b, kmat, nullptr,
                                                  nullptr, 9216, 1024, 1024);
  gemm256<4><<<dim3(144), dim3(512), 0, stream>>>(vln, wv_b, vtmat, nullptr,
                                                  nullptr, 9216, 1024, 1024);
  attn_kernel<<<dim3(4096), dim3(256), 0, stream>>>(qmat, kmat, vtmat, aoh);
  gemm256<2><<<dim3(256), dim3(512), 0, stream>>>(aoh, wo_b, nullptr, pq, pq,
                                                  16384, 1024, 1024);
  ln_rows<<<dim3(16384), dim3(256), 0, stream>>>(pq, norm_g, norm_b, xmat);
  gemm256<3><<<dim3(256), dim3(512), 0, stream>>>(xmat, w1_b, gout, nullptr,
                                                  nullptr, 16384, 1024, 1024);
  gemm256<2><<<dim3(256), dim3(512), 0, stream>>>(gout, w2_b, nullptr, out,
                                                  image_tokens, 16384, 1024, 1024);
}